// Round 6
// baseline (605.531 us; speedup 1.0000x reference)
//
#include <hip/hip_runtime.h>
#include <hip/hip_fp16.h>

#define S_LEN 8192
#define T_LEN 8192
#define D_DIM 256
#define QBLK 128
#define KVBLK 32
#define NQT (S_LEN / QBLK)        // 64
#define KTILE_BYTES 16384         // 32 keys x 256 d x 2B (swizzled image)
#define VTILE_BYTES 16384         // 256 d x 32 keys x 2B (swizzled, pi-permuted image)
#define RESCALE_THR 6.0f          // log2 domain
#define LOG2E 1.44269504f

typedef _Float16 f16x8 __attribute__((ext_vector_type(8)));
typedef float f32x4 __attribute__((ext_vector_type(4)));

struct h4 { _Float16 h[4]; };

#define GLOAD_LDS16(g, l)                                              \
    __builtin_amdgcn_global_load_lds(                                  \
        (const __attribute__((address_space(1))) void*)(g),            \
        (__attribute__((address_space(3))) void*)(l), 16, 0, 0)

#define MFMA16(a, b, c) __builtin_amdgcn_mfma_f32_16x16x32_f16(a, b, c, 0, 0, 0)

// ---------------- Q: fp32 -> f16 row-major, pre-scaled by log2(e) ----------------
__global__ __launch_bounds__(256) void cvt_kernel(const float* __restrict__ in,
                                                  _Float16* __restrict__ out, int n4) {
    int i = blockIdx.x * 256 + threadIdx.x;
    if (i < n4) {
        float4 v = ((const float4*)in)[i];
        h4 o;
        o.h[0] = (_Float16)(v.x * LOG2E); o.h[1] = (_Float16)(v.y * LOG2E);
        o.h[2] = (_Float16)(v.z * LOG2E); o.h[3] = (_Float16)(v.w * LOG2E);
        ((h4*)out)[i] = o;
    }
}

// ------- K -> Kimg: per-32-key tile [32 r][512B], granule swizzle ck^(r&7) -------
__global__ __launch_bounds__(256) void cvt_swz_kernel(const float* __restrict__ in,
                                                      _Float16* __restrict__ img,
                                                      int nchunks) {
    int id = blockIdx.x * 256 + threadIdx.x;
    if (id >= nchunks) return;
    int row = id >> 5, ck = id & 31;
    int t = row >> 5, r = row & 31;
    float4 a = *(const float4*)(in + (size_t)row * D_DIM + ck * 8);
    float4 b = *(const float4*)(in + (size_t)row * D_DIM + ck * 8 + 4);
    f16x8 o;
    o[0] = (_Float16)a.x; o[1] = (_Float16)a.y; o[2] = (_Float16)a.z; o[3] = (_Float16)a.w;
    o[4] = (_Float16)b.x; o[5] = (_Float16)b.y; o[6] = (_Float16)b.z; o[7] = (_Float16)b.w;
    *(f16x8*)((char*)img + (size_t)t * KTILE_BYTES + r * 512 + ((ck ^ (r & 7)) << 4)) = o;
}

// ------- V -> Vimg: per-32-key tile [256 d][64B].
// Granule gk elem j holds key pi(gk*8+j) = (j>>2)*16 + gk*4 + (j&3); granule position
// swizzled gk ^ ((d>>1)&3) -> conflict-free b128 reads. -------
__global__ __launch_bounds__(256) void vt_swz_kernel(const float* __restrict__ V,
                                                     _Float16* __restrict__ Vimg) {
    __shared__ float tile[32][260];
    const int t = blockIdx.x;
#pragma unroll
    for (int i = 0; i < 8; ++i) {
        int idx = i * 256 + threadIdx.x;
        int kr = idx >> 6, c4 = idx & 63;
        float4 v = *(const float4*)(V + ((size_t)t * 32 + kr) * D_DIM + c4 * 4);
        tile[kr][c4 * 4 + 0] = v.x;
        tile[kr][c4 * 4 + 1] = v.y;
        tile[kr][c4 * 4 + 2] = v.z;
        tile[kr][c4 * 4 + 3] = v.w;
    }
    __syncthreads();
#pragma unroll
    for (int i = 0; i < 4; ++i) {
        int gid = i * 256 + threadIdx.x;
        int d = gid >> 2, gk = gid & 3;
        f16x8 o;
#pragma unroll
        for (int j = 0; j < 8; ++j)
            o[j] = (_Float16)tile[(j >> 2) * 16 + gk * 4 + (j & 3)][d];
        *(f16x8*)((char*)Vimg + (size_t)t * VTILE_BYTES + d * 64 +
                  ((gk ^ ((d >> 1) & 3)) << 4)) = o;
    }
}

// ---------------- flash attention ----------------
// 4 waves x 32 q-rows (M_rep=2). Single-buffered sK(16K)+sV(16K) = 32KB LDS ->
// 4 blocks/CU at TSPLIT=16 (grid 1024 = one exact scheduling round, 16 waves/CU).
// Schedule per tile: vmcnt(0);B_A (publish K(kt)) | issue V(kt) | QK+softmax |
// vmcnt(0);B_B (publish V(kt), sK safe) | issue K(kt+1) | PV.
// Every drained load is >= one compute phase old -> drains are cheap.
template <int TSPLIT_>
__global__ __launch_bounds__(256, 4) void attn_kernel(
    const _Float16* __restrict__ Qh, const _Float16* __restrict__ Kimg,
    const _Float16* __restrict__ Vimg, _Float16* __restrict__ Opart,
    float* __restrict__ ml) {
    constexpr int NKV_ = (T_LEN / TSPLIT_) / KVBLK;
    __shared__ __align__(16) char smem[32768];  // sK@0, sV@16K
    char* sK = smem;
    char* sV = smem + 16384;
    const int tid = threadIdx.x;
    const int wave = tid >> 6, lane = tid & 63;
    const int g = lane >> 4, c = lane & 15;
    const int qtile = blockIdx.x, split = blockIdx.y;
    const int tile0 = split * NKV_;
    const int othr = tid * 16;  // 256 threads x 16B = 4KB per staging round

    // ---- Q B-fragments: B[n=q=c][k = ks*32 + g*8 + j] ----
    f16x8 qf[2][8];
    {
        const size_t qrow0 = (size_t)qtile * QBLK + wave * 32 + c;
#pragma unroll
        for (int mi = 0; mi < 2; ++mi)
#pragma unroll
            for (int ks = 0; ks < 8; ++ks)
                qf[mi][ks] =
                    *(const f16x8*)(Qh + (qrow0 + mi * 16) * D_DIM + (ks * 4 + g) * 8);
    }

    // ---- prologue: stage K(0) ----
    {
        const char* Kt = (const char*)Kimg + (size_t)tile0 * KTILE_BYTES;
#pragma unroll
        for (int i = 0; i < 4; ++i) GLOAD_LDS16(Kt + i * 4096 + othr, sK + i * 4096 + othr);
    }

    f32x4 acc[2][16];
#pragma unroll
    for (int mi = 0; mi < 2; ++mi)
#pragma unroll
        for (int dt = 0; dt < 16; ++dt) acc[mi][dt] = (f32x4){0.f, 0.f, 0.f, 0.f};
    float m[2] = {-1e30f, -1e30f}, l[2] = {0.f, 0.f};

    for (int kt = 0; kt < NKV_; ++kt) {
        asm volatile("s_waitcnt vmcnt(0)" ::: "memory");  // K(kt) landed (aged >= PV span)
        __builtin_amdgcn_s_barrier();                     // B_A: publish K(kt); sV safe

        // issue V(kt) -> sV: flies under QK+softmax
        {
            const char* Vt = (const char*)Vimg + (size_t)(tile0 + kt) * VTILE_BYTES;
#pragma unroll
            for (int i = 0; i < 4; ++i)
                GLOAD_LDS16(Vt + i * 4096 + othr, sV + i * 4096 + othr);
        }

        // ---- QK^T swapped: st[mi][ct] = S^T[key=ct*16+g*4+r][q=mi*16+c] ----
        f32x4 st[2][2];
#pragma unroll
        for (int mi = 0; mi < 2; ++mi)
#pragma unroll
            for (int ct = 0; ct < 2; ++ct) st[mi][ct] = (f32x4){0.f, 0.f, 0.f, 0.f};
        __builtin_amdgcn_s_setprio(1);
#pragma unroll
        for (int ks = 0; ks < 8; ++ks) {
            const int ck = ((ks * 4 + g) ^ (c & 7)) << 4;
            f16x8 kf0 = *(const f16x8*)(sK + c * 512 + ck);
            f16x8 kf1 = *(const f16x8*)(sK + 8192 + c * 512 + ck);
            st[0][0] = MFMA16(kf0, qf[0][ks], st[0][0]);
            st[0][1] = MFMA16(kf1, qf[0][ks], st[0][1]);
            st[1][0] = MFMA16(kf0, qf[1][ks], st[1][0]);
            st[1][1] = MFMA16(kf1, qf[1][ks], st[1][1]);
        }
        __builtin_amdgcn_s_setprio(0);

        // ---- online softmax, base-2 (row q = c; keys spread over g,ct,r) ----
        union PU { unsigned int u[4]; f16x8 v; };
        PU pu[2];
#pragma unroll
        for (int mi = 0; mi < 2; ++mi) {
            float pm = st[mi][0][0];
#pragma unroll
            for (int ct = 0; ct < 2; ++ct)
#pragma unroll
                for (int r = 0; r < 4; ++r) pm = fmaxf(pm, st[mi][ct][r]);
            pm = fmaxf(pm, __shfl_xor(pm, 16));
            pm = fmaxf(pm, __shfl_xor(pm, 32));
            if (__any(pm > m[mi] + RESCALE_THR)) {
                float mn = fmaxf(m[mi], pm);
                float sc = exp2f(m[mi] - mn);
                m[mi] = mn;
                l[mi] *= sc;
                float fr[4];
#pragma unroll
                for (int r = 0; r < 4; ++r) fr[r] = __shfl(sc, (g << 4) | (g * 4 + r));
#pragma unroll
                for (int dt = 0; dt < 16; ++dt)
#pragma unroll
                    for (int r = 0; r < 4; ++r) acc[mi][dt][r] *= fr[r];
            }
            float rs = 0.f;
#pragma unroll
            for (int ct = 0; ct < 2; ++ct)
#pragma unroll
                for (int r = 0; r < 4; ++r) {
                    float p = exp2f(st[mi][ct][r] - m[mi]);
                    st[mi][ct][r] = p;
                    rs += p;
                }
            rs += __shfl_xor(rs, 16);
            rs += __shfl_xor(rs, 32);
            l[mi] += rs;
            // pack P in-lane: A'[q=c][kslot g*8+j], pi(g*8+j)=(j>>2)*16+g*4+(j&3)
            pu[mi].u[0] = __builtin_bit_cast(
                unsigned int, __builtin_amdgcn_cvt_pkrtz(st[mi][0][0], st[mi][0][1]));
            pu[mi].u[1] = __builtin_bit_cast(
                unsigned int, __builtin_amdgcn_cvt_pkrtz(st[mi][0][2], st[mi][0][3]));
            pu[mi].u[2] = __builtin_bit_cast(
                unsigned int, __builtin_amdgcn_cvt_pkrtz(st[mi][1][0], st[mi][1][1]));
            pu[mi].u[3] = __builtin_bit_cast(
                unsigned int, __builtin_amdgcn_cvt_pkrtz(st[mi][1][2], st[mi][1][3]));
        }

        asm volatile("s_waitcnt vmcnt(0)" ::: "memory");  // V(kt) landed (aged QK+softmax)
        __builtin_amdgcn_s_barrier();                     // B_B: publish V(kt); sK safe

        // issue K(kt+1) -> sK: flies under PV
        if (kt + 1 < NKV_) {
            const char* Kt = (const char*)Kimg + (size_t)(tile0 + kt + 1) * KTILE_BYTES;
#pragma unroll
            for (int i = 0; i < 4; ++i)
                GLOAD_LDS16(Kt + i * 4096 + othr, sK + i * 4096 + othr);
        }

        // ---- PV: acc[mi][dt] += P' * V'  (pi-permuted k-axis on both sides) ----
        __builtin_amdgcn_s_setprio(1);
#pragma unroll
        for (int dt = 0; dt < 16; ++dt) {
            const int d = dt * 16 + c;
            f16x8 vf = *(const f16x8*)(sV + d * 64 + ((g ^ ((c >> 1) & 3)) << 4));
            acc[0][dt] = MFMA16(pu[0].v, vf, acc[0][dt]);
            acc[1][dt] = MFMA16(pu[1].v, vf, acc[1][dt]);
        }
        __builtin_amdgcn_s_setprio(0);
    }

    // ---- epilogue: unnormalized partial O (f16) + (m,l) ----
    _Float16* Ob = Opart + (size_t)(qtile * TSPLIT_ + split) * QBLK * D_DIM;
#pragma unroll
    for (int mi = 0; mi < 2; ++mi)
#pragma unroll
        for (int dt = 0; dt < 16; ++dt)
#pragma unroll
            for (int r = 0; r < 4; ++r) {
                int row = wave * 32 + mi * 16 + g * 4 + r;
                int col = dt * 16 + c;
                Ob[(size_t)row * D_DIM + col] = (_Float16)acc[mi][dt][r];
            }
    if (g == 0) {
        float* mlb = ml + (size_t)((qtile * TSPLIT_ + split) * QBLK) * 2;
#pragma unroll
        for (int mi = 0; mi < 2; ++mi) {
            int row = wave * 32 + mi * 16 + c;
            mlb[row * 2 + 0] = m[mi];
            mlb[row * 2 + 1] = l[mi];
        }
    }
}

// ---------------- combine TSPLIT partials (base-2 stats) ----------------
template <int TSPLIT_>
__global__ __launch_bounds__(256) void combine_kernel(const _Float16* __restrict__ Opart,
                                                      const float* __restrict__ ml,
                                                      float* __restrict__ out) {
    int r = blockIdx.x;
    int qtile = r >> 7, rl = r & 127;
    int d = threadIdx.x;
    float mv[TSPLIT_], lv[TSPLIT_];
    float M = -1e30f;
#pragma unroll
    for (int s = 0; s < TSPLIT_; ++s) {
        const float* mlb = ml + (size_t)((qtile * TSPLIT_ + s) * QBLK + rl) * 2;
        mv[s] = mlb[0];
        lv[s] = mlb[1];
        M = fmaxf(M, mv[s]);
    }
    float num = 0.f, den = 0.f;
#pragma unroll
    for (int s = 0; s < TSPLIT_; ++s) {
        float w = exp2f(mv[s] - M);
        num += w * (float)Opart[((size_t)(qtile * TSPLIT_ + s) * QBLK + rl) * D_DIM + d];
        den += w * lv[s];
    }
    out[(size_t)r * D_DIM + d] = num / den;
}

extern "C" void kernel_launch(void* const* d_in, const int* in_sizes, int n_in,
                              void* d_out, int out_size, void* d_ws, size_t ws_size,
                              hipStream_t stream) {
    const float* Q = (const float*)d_in[0];
    const float* K = (const float*)d_in[1];
    const float* V = (const float*)d_in[2];
    float* out = (float*)d_out;
    char* ws = (char*)d_ws;

    _Float16* Qh = (_Float16*)ws;                    // 4MB row-major f16 (x log2e)
    _Float16* Kimg = (_Float16*)(ws + (4 << 20));    // 4MB swizzled 32-key tiles
    _Float16* Vimg = (_Float16*)(ws + (8 << 20));    // 4MB swizzled pi-permuted tiles
    _Float16* Opart = (_Float16*)(ws + (12 << 20));  // f16 partials (TSPLIT*4MB)
    // ml placed after Opart, per path below

    const int n4 = S_LEN * D_DIM / 4;
    const int nchunks = S_LEN * D_DIM / 8;
    cvt_kernel<<<n4 / 256, 256, 0, stream>>>(Q, Qh, n4);
    cvt_swz_kernel<<<nchunks / 256, 256, 0, stream>>>(K, Kimg, nchunks);
    vt_swz_kernel<<<T_LEN / 32, 256, 0, stream>>>(V, Vimg);

    if (ws_size >= ((size_t)80 << 20)) {
        // TSPLIT=16: Opart 64MB @12MB, ml 1MB @76MB  (grid 1024 = 4 blocks/CU)
        float* ml = (float*)(ws + ((size_t)76 << 20));
        dim3 ag(NQT, 16);
        attn_kernel<16><<<ag, 256, 0, stream>>>(Qh, Kimg, Vimg, Opart, ml);
        combine_kernel<16><<<S_LEN, 256, 0, stream>>>(Opart, ml, out);
    } else {
        // TSPLIT=8 fallback: Opart 32MB @12MB, ml @44MB
        float* ml = (float*)(ws + ((size_t)44 << 20));
        dim3 ag(NQT, 8);
        attn_kernel<8><<<ag, 256, 0, stream>>>(Qh, Kimg, Vimg, Opart, ml);
        combine_kernel<8><<<S_LEN, 256, 0, stream>>>(Opart, ml, out);
    }
}

// Round 7
// 122.322 us; speedup vs baseline: 4.9503x; 4.9503x over previous
//
#include <hip/hip_runtime.h>
#include <hip/hip_fp16.h>

#define S_LEN 8192
#define T_LEN 8192
#define D_DIM 256
#define QBLK 128
#define KVBLK 32
#define NQT (S_LEN / QBLK)        // 64
#define KTILE_BYTES 16384         // 32 keys x 256 d x 2B (swizzled image)
#define VTILE_BYTES 16384         // 256 d x 32 keys x 2B (swizzled, pi-permuted image)
#define RESCALE_THR 6.0f          // log2 domain
#define LOG2E 1.44269504f

typedef _Float16 f16x8 __attribute__((ext_vector_type(8)));
typedef float f32x4 __attribute__((ext_vector_type(4)));

struct h4 { _Float16 h[4]; };

#define GLOAD_LDS16(g, l)                                              \
    __builtin_amdgcn_global_load_lds(                                  \
        (const __attribute__((address_space(1))) void*)(g),            \
        (__attribute__((address_space(3))) void*)(l), 16, 0, 0)

#define MFMA16(a, b, c) __builtin_amdgcn_mfma_f32_16x16x32_f16(a, b, c, 0, 0, 0)

// ---------------- Q: fp32 -> f16 row-major, pre-scaled by log2(e) ----------------
__global__ __launch_bounds__(256) void cvt_kernel(const float* __restrict__ in,
                                                  _Float16* __restrict__ out, int n4) {
    int i = blockIdx.x * 256 + threadIdx.x;
    if (i < n4) {
        float4 v = ((const float4*)in)[i];
        h4 o;
        o.h[0] = (_Float16)(v.x * LOG2E); o.h[1] = (_Float16)(v.y * LOG2E);
        o.h[2] = (_Float16)(v.z * LOG2E); o.h[3] = (_Float16)(v.w * LOG2E);
        ((h4*)out)[i] = o;
    }
}

// ------- K -> Kimg: per-32-key tile [32 r][512B], granule swizzle ck^(r&7) -------
__global__ __launch_bounds__(256) void cvt_swz_kernel(const float* __restrict__ in,
                                                      _Float16* __restrict__ img,
                                                      int nchunks) {
    int id = blockIdx.x * 256 + threadIdx.x;
    if (id >= nchunks) return;
    int row = id >> 5, ck = id & 31;
    int t = row >> 5, r = row & 31;
    float4 a = *(const float4*)(in + (size_t)row * D_DIM + ck * 8);
    float4 b = *(const float4*)(in + (size_t)row * D_DIM + ck * 8 + 4);
    f16x8 o;
    o[0] = (_Float16)a.x; o[1] = (_Float16)a.y; o[2] = (_Float16)a.z; o[3] = (_Float16)a.w;
    o[4] = (_Float16)b.x; o[5] = (_Float16)b.y; o[6] = (_Float16)b.z; o[7] = (_Float16)b.w;
    *(f16x8*)((char*)img + (size_t)t * KTILE_BYTES + r * 512 + ((ck ^ (r & 7)) << 4)) = o;
}

// ------- V -> Vimg: per-32-key tile [256 d][64B].
// Granule gk elem j holds key pi(gk*8+j) = (j>>2)*16 + gk*4 + (j&3); granule position
// swizzled gk ^ ((d>>1)&3) -> conflict-free b128 reads. -------
__global__ __launch_bounds__(256) void vt_swz_kernel(const float* __restrict__ V,
                                                     _Float16* __restrict__ Vimg) {
    __shared__ float tile[32][260];
    const int t = blockIdx.x;
#pragma unroll
    for (int i = 0; i < 8; ++i) {
        int idx = i * 256 + threadIdx.x;
        int kr = idx >> 6, c4 = idx & 63;
        float4 v = *(const float4*)(V + ((size_t)t * 32 + kr) * D_DIM + c4 * 4);
        tile[kr][c4 * 4 + 0] = v.x;
        tile[kr][c4 * 4 + 1] = v.y;
        tile[kr][c4 * 4 + 2] = v.z;
        tile[kr][c4 * 4 + 3] = v.w;
    }
    __syncthreads();
#pragma unroll
    for (int i = 0; i < 4; ++i) {
        int gid = i * 256 + threadIdx.x;
        int d = gid >> 2, gk = gid & 3;
        f16x8 o;
#pragma unroll
        for (int j = 0; j < 8; ++j)
            o[j] = (_Float16)tile[(j >> 2) * 16 + gk * 4 + (j & 3)][d];
        *(f16x8*)((char*)Vimg + (size_t)t * VTILE_BYTES + d * 64 +
                  ((gk ^ ((d >> 1) & 3)) << 4)) = o;
    }
}

// ---------------- flash attention (R5 structure restored) ----------------
// 4 waves x 32 q-rows (M_rep=2). 64KB LDS: dbuf K(2x16K)+V(2x16K) -> 2 blocks/CU
// (register ceiling: live set ~256 regs at M_rep=2 -> NEVER target >2 blocks/CU).
// Double-buffered, counted vmcnt(8), 2 barriers/tile. 1D grid bid=qtile*TSPLIT+split
// so consecutive bids round-robin XCDs by split -> per-XCD L2 keeps its KV chunk.
// Softmax: defer-l (per-lane partials, reduced at epilogue) + max-reduce only
// inside the (wave-uniform) rescale branch.
template <int TSPLIT_>
__global__ __launch_bounds__(256, 2) void attn_kernel(
    const _Float16* __restrict__ Qh, const _Float16* __restrict__ Kimg,
    const _Float16* __restrict__ Vimg, _Float16* __restrict__ Opart,
    float* __restrict__ ml) {
    constexpr int NKV_ = (T_LEN / TSPLIT_) / KVBLK;
    __shared__ __align__(16) char smem[65536];  // sK[2]@0,16K ; sV[2]@32K,48K
    const int tid = threadIdx.x;
    const int wave = tid >> 6, lane = tid & 63;
    const int g = lane >> 4, c = lane & 15;
    const int bid = blockIdx.x;
    const int qtile = bid / TSPLIT_, split = bid % TSPLIT_;
    const int tile0 = split * NKV_;

    // ---- Q B-fragments: B[n=q=c][k = ks*32 + g*8 + j] ----
    f16x8 qf[2][8];
    {
        const size_t qrow0 = (size_t)qtile * QBLK + wave * 32 + c;
#pragma unroll
        for (int mi = 0; mi < 2; ++mi)
#pragma unroll
            for (int ks = 0; ks < 8; ++ks)
                qf[mi][ks] =
                    *(const f16x8*)(Qh + (qrow0 + mi * 16) * D_DIM + (ks * 4 + g) * 8);
    }
    asm volatile("s_waitcnt vmcnt(0)" ::: "memory");  // Q out of the vmcnt pipeline count

    f32x4 acc[2][16];
#pragma unroll
    for (int mi = 0; mi < 2; ++mi)
#pragma unroll
        for (int dt = 0; dt < 16; ++dt) acc[mi][dt] = (f32x4){0.f, 0.f, 0.f, 0.f};
    float m[2] = {-1e30f, -1e30f};
    float l[2] = {0.f, 0.f};  // per-lane partial sums (q-row c, keys of this lane)

    const int othr = tid * 16;  // 256 threads x 16B = 4KB per staging round

    // ---- prologue: stage tile0 into buffer 0 (8 loads in flight) ----
    {
        const char* Kt = (const char*)Kimg + (size_t)tile0 * KTILE_BYTES;
        const char* Vt = (const char*)Vimg + (size_t)tile0 * VTILE_BYTES;
#pragma unroll
        for (int i = 0; i < 4; ++i) {
            GLOAD_LDS16(Kt + i * 4096 + othr, smem + i * 4096 + othr);
            GLOAD_LDS16(Vt + i * 4096 + othr, smem + 32768 + i * 4096 + othr);
        }
    }

    for (int kt = 0; kt < NKV_; ++kt) {
        const int cur = kt & 1;
        if (kt + 1 < NKV_) {
            const char* Kt = (const char*)Kimg + (size_t)(tile0 + kt + 1) * KTILE_BYTES;
            const char* Vt = (const char*)Vimg + (size_t)(tile0 + kt + 1) * VTILE_BYTES;
            const int nb = (cur ^ 1) * 16384;
#pragma unroll
            for (int i = 0; i < 4; ++i) {
                GLOAD_LDS16(Kt + i * 4096 + othr, smem + nb + i * 4096 + othr);
                GLOAD_LDS16(Vt + i * 4096 + othr, smem + 32768 + nb + i * 4096 + othr);
            }
            asm volatile("s_waitcnt vmcnt(8)" ::: "memory");  // cur landed; next in flight
        } else {
            asm volatile("s_waitcnt vmcnt(0)" ::: "memory");
        }
        __builtin_amdgcn_s_barrier();

        const char* sK = smem + cur * 16384;
        const char* sV = smem + 32768 + cur * 16384;

        // ---- QK^T swapped: st[mi][ct] = S^T[key=ct*16+g*4+r][q=mi*16+c] ----
        f32x4 st[2][2];
#pragma unroll
        for (int mi = 0; mi < 2; ++mi)
#pragma unroll
            for (int ct = 0; ct < 2; ++ct) st[mi][ct] = (f32x4){0.f, 0.f, 0.f, 0.f};
        __builtin_amdgcn_s_setprio(1);
#pragma unroll
        for (int ks = 0; ks < 8; ++ks) {
            const int ck = ((ks * 4 + g) ^ (c & 7)) << 4;
            f16x8 kf0 = *(const f16x8*)(sK + c * 512 + ck);
            f16x8 kf1 = *(const f16x8*)(sK + 8192 + c * 512 + ck);
            st[0][0] = MFMA16(kf0, qf[0][ks], st[0][0]);
            st[0][1] = MFMA16(kf1, qf[0][ks], st[0][1]);
            st[1][0] = MFMA16(kf0, qf[1][ks], st[1][0]);
            st[1][1] = MFMA16(kf1, qf[1][ks], st[1][1]);
        }
        __builtin_amdgcn_s_setprio(0);

        // ---- online softmax, base-2 (q-row = c; keys spread over g,ct,r) ----
        union PU { unsigned int u[4]; f16x8 v; };
        PU pu[2];
#pragma unroll
        for (int mi = 0; mi < 2; ++mi) {
            // per-lane partial max (enough for the trigger test)
            float pm = fmaxf(fmaxf(fmaxf(st[mi][0][0], st[mi][0][1]),
                                   fmaxf(st[mi][0][2], st[mi][0][3])),
                             fmaxf(fmaxf(st[mi][1][0], st[mi][1][1]),
                                   fmaxf(st[mi][1][2], st[mi][1][3])));
            if (__any(pm > m[mi] + RESCALE_THR)) {
                // full row max only when actually rescaling (wave-uniform branch)
                pm = fmaxf(pm, __shfl_xor(pm, 16));
                pm = fmaxf(pm, __shfl_xor(pm, 32));
                float mn = fmaxf(m[mi], pm);
                float sc = exp2f(m[mi] - mn);  // per-q-row (lane c)
                m[mi] = mn;
                l[mi] *= sc;
                float fr[4];
#pragma unroll
                for (int r = 0; r < 4; ++r) fr[r] = __shfl(sc, (g << 4) | (g * 4 + r));
#pragma unroll
                for (int dt = 0; dt < 16; ++dt)
#pragma unroll
                    for (int r = 0; r < 4; ++r) acc[mi][dt][r] *= fr[r];
            }
            float rs = 0.f;
#pragma unroll
            for (int ct = 0; ct < 2; ++ct)
#pragma unroll
                for (int r = 0; r < 4; ++r) {
                    float p = exp2f(st[mi][ct][r] - m[mi]);
                    st[mi][ct][r] = p;
                    rs += p;
                }
            l[mi] += rs;  // per-lane partial; reduced once at epilogue
            // pack P in-lane: A'[q=c][kslot g*8+j], pi(g*8+j)=(j>>2)*16+g*4+(j&3)
            pu[mi].u[0] = __builtin_bit_cast(
                unsigned int, __builtin_amdgcn_cvt_pkrtz(st[mi][0][0], st[mi][0][1]));
            pu[mi].u[1] = __builtin_bit_cast(
                unsigned int, __builtin_amdgcn_cvt_pkrtz(st[mi][0][2], st[mi][0][3]));
            pu[mi].u[2] = __builtin_bit_cast(
                unsigned int, __builtin_amdgcn_cvt_pkrtz(st[mi][1][0], st[mi][1][1]));
            pu[mi].u[3] = __builtin_bit_cast(
                unsigned int, __builtin_amdgcn_cvt_pkrtz(st[mi][1][2], st[mi][1][3]));
        }

        // ---- PV: acc[mi][dt] += P' * V'  (pi-permuted k-axis on both sides) ----
        __builtin_amdgcn_s_setprio(1);
#pragma unroll
        for (int dt = 0; dt < 16; ++dt) {
            const int d = dt * 16 + c;
            f16x8 vf = *(const f16x8*)(sV + d * 64 + ((g ^ ((c >> 1) & 3)) << 4));
            acc[0][dt] = MFMA16(pu[0].v, vf, acc[0][dt]);
            acc[1][dt] = MFMA16(pu[1].v, vf, acc[1][dt]);
        }
        __builtin_amdgcn_s_setprio(0);

        __builtin_amdgcn_s_barrier();  // all reads of cur done before next stage overwrites
    }

    // ---- epilogue: unnormalized partial O (f16) + (m,l) ----
    _Float16* Ob = Opart + (size_t)(qtile * TSPLIT_ + split) * QBLK * D_DIM;
#pragma unroll
    for (int mi = 0; mi < 2; ++mi)
#pragma unroll
        for (int dt = 0; dt < 16; ++dt)
#pragma unroll
            for (int r = 0; r < 4; ++r) {
                int row = wave * 32 + mi * 16 + g * 4 + r;
                int col = dt * 16 + c;
                Ob[(size_t)row * D_DIM + col] = (_Float16)acc[mi][dt][r];
            }
    // finish the deferred l reduction (sum across the 4 g-groups per q-row c)
#pragma unroll
    for (int mi = 0; mi < 2; ++mi) {
        l[mi] += __shfl_xor(l[mi], 16);
        l[mi] += __shfl_xor(l[mi], 32);
    }
    if (g == 0) {
        float* mlb = ml + (size_t)((qtile * TSPLIT_ + split) * QBLK) * 2;
#pragma unroll
        for (int mi = 0; mi < 2; ++mi) {
            int row = wave * 32 + mi * 16 + c;
            mlb[row * 2 + 0] = m[mi];
            mlb[row * 2 + 1] = l[mi];
        }
    }
}

// ---------------- combine TSPLIT partials (base-2 stats) ----------------
template <int TSPLIT_>
__global__ __launch_bounds__(256) void combine_kernel(const _Float16* __restrict__ Opart,
                                                      const float* __restrict__ ml,
                                                      float* __restrict__ out) {
    int r = blockIdx.x;
    int qtile = r >> 7, rl = r & 127;
    int d = threadIdx.x;
    float mv[TSPLIT_], lv[TSPLIT_];
    float M = -1e30f;
#pragma unroll
    for (int s = 0; s < TSPLIT_; ++s) {
        const float* mlb = ml + (size_t)((qtile * TSPLIT_ + s) * QBLK + rl) * 2;
        mv[s] = mlb[0];
        lv[s] = mlb[1];
        M = fmaxf(M, mv[s]);
    }
    float num = 0.f, den = 0.f;
#pragma unroll
    for (int s = 0; s < TSPLIT_; ++s) {
        float w = exp2f(mv[s] - M);
        num += w * (float)Opart[((size_t)(qtile * TSPLIT_ + s) * QBLK + rl) * D_DIM + d];
        den += w * lv[s];
    }
    out[(size_t)r * D_DIM + d] = num / den;
}

extern "C" void kernel_launch(void* const* d_in, const int* in_sizes, int n_in,
                              void* d_out, int out_size, void* d_ws, size_t ws_size,
                              hipStream_t stream) {
    const float* Q = (const float*)d_in[0];
    const float* K = (const float*)d_in[1];
    const float* V = (const float*)d_in[2];
    float* out = (float*)d_out;
    char* ws = (char*)d_ws;

    _Float16* Qh = (_Float16*)ws;                    // 4MB row-major f16 (x log2e)
    _Float16* Kimg = (_Float16*)(ws + (4 << 20));    // 4MB swizzled 32-key tiles
    _Float16* Vimg = (_Float16*)(ws + (8 << 20));    // 4MB swizzled pi-permuted tiles
    _Float16* Opart = (_Float16*)(ws + (12 << 20));  // f16 partials (TSPLIT*4MB)

    const int n4 = S_LEN * D_DIM / 4;
    const int nchunks = S_LEN * D_DIM / 8;
    cvt_kernel<<<n4 / 256, 256, 0, stream>>>(Q, Qh, n4);
    cvt_swz_kernel<<<nchunks / 256, 256, 0, stream>>>(K, Kimg, nchunks);
    vt_swz_kernel<<<T_LEN / 32, 256, 0, stream>>>(V, Vimg);

    if (ws_size >= ((size_t)80 << 20)) {
        // TSPLIT=16: Opart 64MB @12MB, ml 1MB @76MB; grid 1024 (2 resident + 2
        // queued blocks/CU -> turnover desync); bid%16=split -> XCD-local chunks
        float* ml = (float*)(ws + ((size_t)76 << 20));
        attn_kernel<16><<<NQT * 16, 256, 0, stream>>>(Qh, Kimg, Vimg, Opart, ml);
        combine_kernel<16><<<S_LEN, 256, 0, stream>>>(Opart, ml, out);
    } else {
        // TSPLIT=8 fallback: Opart 32MB @12MB, ml @44MB
        float* ml = (float*)(ws + ((size_t)44 << 20));
        attn_kernel<8><<<NQT * 8, 256, 0, stream>>>(Qh, Kimg, Vimg, Opart, ml);
        combine_kernel<8><<<S_LEN, 256, 0, stream>>>(Opart, ml, out);
    }
}

// Round 8
// 108.571 us; speedup vs baseline: 5.5773x; 1.1266x over previous
//
#include <hip/hip_runtime.h>
#include <hip/hip_fp16.h>

#define S_LEN 8192
#define T_LEN 8192
#define D_DIM 256
#define QBLK 64
#define KVBLK 32
#define TSPLIT 8
#define NKV ((T_LEN / TSPLIT) / KVBLK)  // 32 tiles per block
#define NQT (S_LEN / QBLK)              // 128
#define KTILE_BYTES 16384               // 32 keys x 256 d x 2B (linear-read image)
#define VTILE_BYTES 16384               // 256 d x 32 keys x 2B (linear-read image)
#define RESCALE_THR 6.0f                // log2 domain
#define LOG2E 1.44269504f

typedef _Float16 f16x8 __attribute__((ext_vector_type(8)));
typedef float f32x4 __attribute__((ext_vector_type(4)));

struct h4 { _Float16 h[4]; };

#define GLOAD_LDS16(g, l)                                              \
    __builtin_amdgcn_global_load_lds(                                  \
        (const __attribute__((address_space(1))) void*)(g),            \
        (__attribute__((address_space(3))) void*)(l), 16, 0, 0)

#define MFMA16(a, b, c) __builtin_amdgcn_mfma_f32_16x16x32_f16(a, b, c, 0, 0, 0)

#if __has_builtin(__builtin_amdgcn_exp2f)
#define EXP2(x) __builtin_amdgcn_exp2f(x)
#else
static __device__ __forceinline__ float EXP2(float x) {
    float y;
    asm("v_exp_f32 %0, %1" : "=v"(y) : "v"(x));
    return y;
}
#endif

// ---------------- Q: fp32 -> f16 row-major, pre-scaled by log2(e) ----------------
__global__ __launch_bounds__(256) void cvt_kernel(const float* __restrict__ in,
                                                  _Float16* __restrict__ out, int n4) {
    int i = blockIdx.x * 256 + threadIdx.x;
    if (i < n4) {
        float4 v = ((const float4*)in)[i];
        h4 o;
        o.h[0] = (_Float16)(v.x * LOG2E); o.h[1] = (_Float16)(v.y * LOG2E);
        o.h[2] = (_Float16)(v.z * LOG2E); o.h[3] = (_Float16)(v.w * LOG2E);
        ((h4*)out)[i] = o;
    }
}

// ------- K -> Kimg. Granule (row r, gr) of tile t (gr = dim/8, ks=gr>>2, g=gr&3)
// placed at ks*2048 + (r>>4)*1024 + (r&15)*64 + g*16  -> the QK read of step
// (ks, half) is a CONTIGUOUS 1KB wave-read (zero bank conflicts, zero swizzle VALU).
__global__ __launch_bounds__(256) void cvt_swz_kernel(const float* __restrict__ in,
                                                      _Float16* __restrict__ img,
                                                      int nchunks) {
    int id = blockIdx.x * 256 + threadIdx.x;
    if (id >= nchunks) return;
    int row = id >> 5, gr = id & 31;
    int t = row >> 5, r = row & 31;
    float4 a = *(const float4*)(in + (size_t)row * D_DIM + gr * 8);
    float4 b = *(const float4*)(in + (size_t)row * D_DIM + gr * 8 + 4);
    f16x8 o;
    o[0] = (_Float16)a.x; o[1] = (_Float16)a.y; o[2] = (_Float16)a.z; o[3] = (_Float16)a.w;
    o[4] = (_Float16)b.x; o[5] = (_Float16)b.y; o[6] = (_Float16)b.z; o[7] = (_Float16)b.w;
    *(f16x8*)((char*)img + (size_t)t * KTILE_BYTES + (gr >> 2) * 2048 +
              ((r >> 4) << 10) + ((r & 15) << 6) + ((gr & 3) << 4)) = o;
}

// ------- V -> Vimg. Granule (d, gk) holds keys pi(gk*8+j)=(j>>2)*16+gk*4+(j&3),
// placed at (d>>4)*1024 + gk*256 + (d&15)*16 -> PV read addr = dt*1024 + lane*16
// (literally linear; zero conflicts). -------
__global__ __launch_bounds__(256) void vt_swz_kernel(const float* __restrict__ V,
                                                     _Float16* __restrict__ Vimg) {
    __shared__ float tile[32][260];
    const int t = blockIdx.x;
#pragma unroll
    for (int i = 0; i < 8; ++i) {
        int idx = i * 256 + threadIdx.x;
        int kr = idx >> 6, c4 = idx & 63;
        float4 v = *(const float4*)(V + ((size_t)t * 32 + kr) * D_DIM + c4 * 4);
        tile[kr][c4 * 4 + 0] = v.x;
        tile[kr][c4 * 4 + 1] = v.y;
        tile[kr][c4 * 4 + 2] = v.z;
        tile[kr][c4 * 4 + 3] = v.w;
    }
    __syncthreads();
#pragma unroll
    for (int i = 0; i < 4; ++i) {
        int gid = i * 256 + threadIdx.x;
        int d = gid >> 2, gk = gid & 3;
        f16x8 o;
#pragma unroll
        for (int j = 0; j < 8; ++j)
            o[j] = (_Float16)tile[(j >> 2) * 16 + gk * 4 + (j & 3)][d];
        *(f16x8*)((char*)Vimg + (size_t)t * VTILE_BYTES + ((d >> 4) << 10) +
                  (gk << 8) + ((d & 15) << 4)) = o;
    }
}

// ---------------- flash attention ----------------
// 2 waves x 32 q-rows (M_rep=2); 32KB LDS single-buffered -> 4 independent
// blocks/CU (8 waves, 4 barrier domains: convoy-breaking). A/B schedule:
//   vmcnt(0);B_A (K(kt) ready, sV free) | issue V(kt) | QK+softmax |
//   vmcnt(0);B_B (V(kt) ready, sK free) | issue K(kt+1) | PV.
// Every drain is >= one compute phase old; cross-block desync fills stalls.
__global__ __launch_bounds__(128, 2) void attn_kernel(
    const _Float16* __restrict__ Qh, const _Float16* __restrict__ Kimg,
    const _Float16* __restrict__ Vimg, _Float16* __restrict__ Opart,
    float* __restrict__ ml) {
    __shared__ __align__(16) char smem[32768];  // sK@0, sV@16K
    char* sK = smem;
    char* sV = smem + 16384;
    const int tid = threadIdx.x;
    const int wave = tid >> 6, lane = tid & 63;
    const int g = lane >> 4, c = lane & 15;
    const int qtile = blockIdx.x, split = blockIdx.y;
    const int tile0 = split * NKV;
    const int othr = tid * 16;                              // staging: 2KB per round
    const int kbase = ((lane & 15) << 6) | ((lane >> 4) << 4);  // c*64 + g*16
    const int vbase = lane << 4;

    // ---- Q B-fragments: B[n=q=c][k = ks*32 + g*8 + j] ----
    f16x8 qf[2][8];
    {
        const size_t qrow0 = (size_t)qtile * QBLK + wave * 32 + c;
#pragma unroll
        for (int mi = 0; mi < 2; ++mi)
#pragma unroll
            for (int ks = 0; ks < 8; ++ks)
                qf[mi][ks] =
                    *(const f16x8*)(Qh + (qrow0 + mi * 16) * D_DIM + (ks * 4 + g) * 8);
    }

    // ---- prologue: stage K(0) ----
    {
        const char* Kt = (const char*)Kimg + (size_t)tile0 * KTILE_BYTES;
#pragma unroll
        for (int i = 0; i < 8; ++i) GLOAD_LDS16(Kt + i * 2048 + othr, sK + i * 2048 + othr);
    }

    f32x4 acc[2][16];
#pragma unroll
    for (int mi = 0; mi < 2; ++mi)
#pragma unroll
        for (int dt = 0; dt < 16; ++dt) acc[mi][dt] = (f32x4){0.f, 0.f, 0.f, 0.f};
    float m[2] = {-1e30f, -1e30f};
    float l[2] = {0.f, 0.f};  // per-lane partials, reduced at epilogue

    for (int kt = 0; kt < NKV; ++kt) {
        asm volatile("s_waitcnt vmcnt(0)" ::: "memory");  // K(kt) (+Q first iter) landed
        __builtin_amdgcn_s_barrier();                     // B_A: K(kt) visible; sV free

        // issue V(kt): flies under QK + softmax
        {
            const char* Vt = (const char*)Vimg + (size_t)(tile0 + kt) * VTILE_BYTES;
#pragma unroll
            for (int i = 0; i < 8; ++i)
                GLOAD_LDS16(Vt + i * 2048 + othr, sV + i * 2048 + othr);
        }

        // ---- QK^T swapped: st[mi][ct] = S^T[key=ct*16+g*4+r][q=mi*16+c] ----
        f32x4 st[2][2];
#pragma unroll
        for (int mi = 0; mi < 2; ++mi)
#pragma unroll
            for (int ct = 0; ct < 2; ++ct) st[mi][ct] = (f32x4){0.f, 0.f, 0.f, 0.f};
        __builtin_amdgcn_s_setprio(1);
#pragma unroll
        for (int ks = 0; ks < 8; ++ks) {
            f16x8 kf0 = *(const f16x8*)(sK + ks * 2048 + kbase);
            f16x8 kf1 = *(const f16x8*)(sK + ks * 2048 + 1024 + kbase);
            st[0][0] = MFMA16(kf0, qf[0][ks], st[0][0]);
            st[0][1] = MFMA16(kf1, qf[0][ks], st[0][1]);
            st[1][0] = MFMA16(kf0, qf[1][ks], st[1][0]);
            st[1][1] = MFMA16(kf1, qf[1][ks], st[1][1]);
        }
        __builtin_amdgcn_s_setprio(0);

        // ---- online softmax, base-2 (q-row = c; keys spread over g,ct,r) ----
        union PU { unsigned int u[4]; f16x8 v; };
        PU pu[2];
#pragma unroll
        for (int mi = 0; mi < 2; ++mi) {
            float pm = fmaxf(fmaxf(fmaxf(st[mi][0][0], st[mi][0][1]),
                                   fmaxf(st[mi][0][2], st[mi][0][3])),
                             fmaxf(fmaxf(st[mi][1][0], st[mi][1][1]),
                                   fmaxf(st[mi][1][2], st[mi][1][3])));
            if (__any(pm > m[mi] + RESCALE_THR)) {
                pm = fmaxf(pm, __shfl_xor(pm, 16));
                pm = fmaxf(pm, __shfl_xor(pm, 32));
                float mn = fmaxf(m[mi], pm);
                float sc = EXP2(m[mi] - mn);
                m[mi] = mn;
                l[mi] *= sc;
                float fr[4];
#pragma unroll
                for (int r = 0; r < 4; ++r) fr[r] = __shfl(sc, (g << 4) | (g * 4 + r));
#pragma unroll
                for (int dt = 0; dt < 16; ++dt)
#pragma unroll
                    for (int r = 0; r < 4; ++r) acc[mi][dt][r] *= fr[r];
            }
            float rs = 0.f;
#pragma unroll
            for (int ct = 0; ct < 2; ++ct)
#pragma unroll
                for (int r = 0; r < 4; ++r) {
                    float p = EXP2(st[mi][ct][r] - m[mi]);
                    st[mi][ct][r] = p;
                    rs += p;
                }
            l[mi] += rs;
            // pack P in-lane: A'[q=c][kslot g*8+j], pi(g*8+j)=(j>>2)*16+g*4+(j&3)
            pu[mi].u[0] = __builtin_bit_cast(
                unsigned int, __builtin_amdgcn_cvt_pkrtz(st[mi][0][0], st[mi][0][1]));
            pu[mi].u[1] = __builtin_bit_cast(
                unsigned int, __builtin_amdgcn_cvt_pkrtz(st[mi][0][2], st[mi][0][3]));
            pu[mi].u[2] = __builtin_bit_cast(
                unsigned int, __builtin_amdgcn_cvt_pkrtz(st[mi][1][0], st[mi][1][1]));
            pu[mi].u[3] = __builtin_bit_cast(
                unsigned int, __builtin_amdgcn_cvt_pkrtz(st[mi][1][2], st[mi][1][3]));
        }

        asm volatile("s_waitcnt vmcnt(0)" ::: "memory");  // V(kt) landed (aged QK+SM)
        __builtin_amdgcn_s_barrier();                     // B_B: V(kt) visible; sK free

        // issue K(kt+1): flies under PV
        if (kt + 1 < NKV) {
            const char* Kt = (const char*)Kimg + (size_t)(tile0 + kt + 1) * KTILE_BYTES;
#pragma unroll
            for (int i = 0; i < 8; ++i)
                GLOAD_LDS16(Kt + i * 2048 + othr, sK + i * 2048 + othr);
        }

        // ---- PV: acc[mi][dt] += P' * V'  (linear 1KB wave-reads) ----
        __builtin_amdgcn_s_setprio(1);
#pragma unroll
        for (int dt = 0; dt < 16; ++dt) {
            f16x8 vf = *(const f16x8*)(sV + dt * 1024 + vbase);
            acc[0][dt] = MFMA16(pu[0].v, vf, acc[0][dt]);
            acc[1][dt] = MFMA16(pu[1].v, vf, acc[1][dt]);
        }
        __builtin_amdgcn_s_setprio(0);
    }

    // ---- epilogue: unnormalized partial O (f16) + (m,l) ----
    _Float16* Ob = Opart + (size_t)(qtile * TSPLIT + split) * QBLK * D_DIM;
#pragma unroll
    for (int mi = 0; mi < 2; ++mi)
#pragma unroll
        for (int dt = 0; dt < 16; ++dt)
#pragma unroll
            for (int r = 0; r < 4; ++r) {
                int row = wave * 32 + mi * 16 + g * 4 + r;
                int col = dt * 16 + c;
                Ob[(size_t)row * D_DIM + col] = (_Float16)acc[mi][dt][r];
            }
#pragma unroll
    for (int mi = 0; mi < 2; ++mi) {
        l[mi] += __shfl_xor(l[mi], 16);
        l[mi] += __shfl_xor(l[mi], 32);
    }
    if (g == 0) {
        float* mlb = ml + (size_t)((qtile * TSPLIT + split) * QBLK) * 2;
#pragma unroll
        for (int mi = 0; mi < 2; ++mi) {
            int row = wave * 32 + mi * 16 + c;
            mlb[row * 2 + 0] = m[mi];
            mlb[row * 2 + 1] = l[mi];
        }
    }
}

// ---------------- combine TSPLIT partials (base-2 stats) ----------------
__global__ __launch_bounds__(256) void combine_kernel(const _Float16* __restrict__ Opart,
                                                      const float* __restrict__ ml,
                                                      float* __restrict__ out) {
    int r = blockIdx.x;
    int qtile = r >> 6, rl = r & 63;  // QBLK=64
    int d = threadIdx.x;
    float mv[TSPLIT], lv[TSPLIT];
    float M = -1e30f;
#pragma unroll
    for (int s = 0; s < TSPLIT; ++s) {
        const float* mlb = ml + (size_t)((qtile * TSPLIT + s) * QBLK + rl) * 2;
        mv[s] = mlb[0];
        lv[s] = mlb[1];
        M = fmaxf(M, mv[s]);
    }
    float num = 0.f, den = 0.f;
#pragma unroll
    for (int s = 0; s < TSPLIT; ++s) {
        float w = EXP2(mv[s] - M);
        num += w * (float)Opart[((size_t)(qtile * TSPLIT + s) * QBLK + rl) * D_DIM + d];
        den += w * lv[s];
    }
    out[(size_t)r * D_DIM + d] = num / den;
}

extern "C" void kernel_launch(void* const* d_in, const int* in_sizes, int n_in,
                              void* d_out, int out_size, void* d_ws, size_t ws_size,
                              hipStream_t stream) {
    const float* Q = (const float*)d_in[0];
    const float* K = (const float*)d_in[1];
    const float* V = (const float*)d_in[2];
    float* out = (float*)d_out;
    char* ws = (char*)d_ws;

    _Float16* Qh = (_Float16*)ws;                    // 4MB row-major f16 (x log2e)
    _Float16* Kimg = (_Float16*)(ws + (4 << 20));    // 4MB linear-read 32-key tiles
    _Float16* Vimg = (_Float16*)(ws + (8 << 20));    // 4MB linear-read transposed tiles
    _Float16* Opart = (_Float16*)(ws + (12 << 20));  // 32MB f16 partials
    float* ml = (float*)(ws + ((size_t)44 << 20));   // 1MB

    const int n4 = S_LEN * D_DIM / 4;
    const int nchunks = S_LEN * D_DIM / 8;
    cvt_kernel<<<n4 / 256, 256, 0, stream>>>(Q, Qh, n4);
    cvt_swz_kernel<<<nchunks / 256, 256, 0, stream>>>(K, Kimg, nchunks);
    vt_swz_kernel<<<T_LEN / 32, 256, 0, stream>>>(V, Vimg);

    dim3 ag(NQT, TSPLIT);  // 128 x 8 = 1024 blocks of 128 threads = 4 blocks/CU
    attn_kernel<<<ag, 128, 0, stream>>>(Qh, Kimg, Vimg, Opart, ml);
    combine_kernel<<<S_LEN, 256, 0, stream>>>(Opart, ml, out);
}

// Round 9
// 105.019 us; speedup vs baseline: 5.7659x; 1.0338x over previous
//
#include <hip/hip_runtime.h>
#include <hip/hip_fp16.h>

#define S_LEN 8192
#define T_LEN 8192
#define D_DIM 256
#define QBLK 128
#define KVBLK 32
#define TSPLIT 8
#define NKV ((T_LEN / TSPLIT) / KVBLK)  // 32 tiles per block
#define NQT (S_LEN / QBLK)              // 64
#define KTILE_BYTES 16384               // 32 keys x 256 d x 2B (linear-read image)
#define VTILE_BYTES 16384               // 256 d x 32 keys x 2B (linear-read image)
#define RESCALE_THR 6.0f                // log2 domain
#define LOG2E 1.44269504f

typedef _Float16 f16x8 __attribute__((ext_vector_type(8)));
typedef float f32x4 __attribute__((ext_vector_type(4)));

struct h4 { _Float16 h[4]; };

#define GLOAD_LDS16(g, l)                                              \
    __builtin_amdgcn_global_load_lds(                                  \
        (const __attribute__((address_space(1))) void*)(g),            \
        (__attribute__((address_space(3))) void*)(l), 16, 0, 0)

#define MFMA16(a, b, c) __builtin_amdgcn_mfma_f32_16x16x32_f16(a, b, c, 0, 0, 0)

#if __has_builtin(__builtin_amdgcn_exp2f)
#define EXP2(x) __builtin_amdgcn_exp2f(x)
#else
static __device__ __forceinline__ float EXP2(float x) {
    float y;
    asm("v_exp_f32 %0, %1" : "=v"(y) : "v"(x));
    return y;
}
#endif

// ---------------- Q: fp32 -> f16 row-major, pre-scaled by log2(e) ----------------
__global__ __launch_bounds__(256) void cvt_kernel(const float* __restrict__ in,
                                                  _Float16* __restrict__ out, int n4) {
    int i = blockIdx.x * 256 + threadIdx.x;
    if (i < n4) {
        float4 v = ((const float4*)in)[i];
        h4 o;
        o.h[0] = (_Float16)(v.x * LOG2E); o.h[1] = (_Float16)(v.y * LOG2E);
        o.h[2] = (_Float16)(v.z * LOG2E); o.h[3] = (_Float16)(v.w * LOG2E);
        ((h4*)out)[i] = o;
    }
}

// ------- K -> Kimg. Granule (row r, gr) of tile t (gr = dim/8, ks=gr>>2, g=gr&3)
// placed at ks*2048 + (r>>4)*1024 + (r&15)*64 + g*16  -> the QK read of step
// (ks, half) is a CONTIGUOUS 1KB wave-read (conflict-free, zero swizzle VALU).
__global__ __launch_bounds__(256) void cvt_swz_kernel(const float* __restrict__ in,
                                                      _Float16* __restrict__ img,
                                                      int nchunks) {
    int id = blockIdx.x * 256 + threadIdx.x;
    if (id >= nchunks) return;
    int row = id >> 5, gr = id & 31;
    int t = row >> 5, r = row & 31;
    float4 a = *(const float4*)(in + (size_t)row * D_DIM + gr * 8);
    float4 b = *(const float4*)(in + (size_t)row * D_DIM + gr * 8 + 4);
    f16x8 o;
    o[0] = (_Float16)a.x; o[1] = (_Float16)a.y; o[2] = (_Float16)a.z; o[3] = (_Float16)a.w;
    o[4] = (_Float16)b.x; o[5] = (_Float16)b.y; o[6] = (_Float16)b.z; o[7] = (_Float16)b.w;
    *(f16x8*)((char*)img + (size_t)t * KTILE_BYTES + (gr >> 2) * 2048 +
              ((r >> 4) << 10) + ((r & 15) << 6) + ((gr & 3) << 4)) = o;
}

// ------- V -> Vimg. Granule (d, gk) holds keys pi(gk*8+j)=(j>>2)*16+gk*4+(j&3),
// placed at (d>>4)*1024 + gk*256 + (d&15)*16 -> PV read addr = dt*1024 + lane*16
// (literally linear; conflict-free). -------
__global__ __launch_bounds__(256) void vt_swz_kernel(const float* __restrict__ V,
                                                     _Float16* __restrict__ Vimg) {
    __shared__ float tile[32][260];
    const int t = blockIdx.x;
#pragma unroll
    for (int i = 0; i < 8; ++i) {
        int idx = i * 256 + threadIdx.x;
        int kr = idx >> 6, c4 = idx & 63;
        float4 v = *(const float4*)(V + ((size_t)t * 32 + kr) * D_DIM + c4 * 4);
        tile[kr][c4 * 4 + 0] = v.x;
        tile[kr][c4 * 4 + 1] = v.y;
        tile[kr][c4 * 4 + 2] = v.z;
        tile[kr][c4 * 4 + 3] = v.w;
    }
    __syncthreads();
#pragma unroll
    for (int i = 0; i < 4; ++i) {
        int gid = i * 256 + threadIdx.x;
        int d = gid >> 2, gk = gid & 3;
        f16x8 o;
#pragma unroll
        for (int j = 0; j < 8; ++j)
            o[j] = (_Float16)tile[(j >> 2) * 16 + gk * 4 + (j & 3)][d];
        *(f16x8*)((char*)Vimg + (size_t)t * VTILE_BYTES + ((d >> 4) << 10) +
                  (gk << 8) + ((d & 15) << 4)) = o;
    }
}

// ---------------- flash attention ----------------
// 4 waves x 32 q-rows (M_rep=2). 64KB LDS: dbuf K(2x16K)+V(2x16K), counted
// vmcnt(8) (steady state never drains to 0). 2 blocks/CU.
// 1D grid: split = bid&7 -> XCD-local KV chunk (1MB per XCD L2).
// Tile-order STAGGER: online softmax is tile-order-agnostic; co-resident
// blocks (bid, bid+256 -> qtile, qtile+32) start 16 tiles apart -> phases
// interleave instead of convoying (LDS/VALU of one fills MFMA shadow of other).
__global__ __launch_bounds__(256, 2) void attn_kernel(
    const _Float16* __restrict__ Qh, const _Float16* __restrict__ Kimg,
    const _Float16* __restrict__ Vimg, _Float16* __restrict__ Opart,
    float* __restrict__ ml) {
    __shared__ __align__(16) char smem[65536];  // sK[2]@0,16K ; sV[2]@32K,48K
    const int tid = threadIdx.x;
    const int wave = tid >> 6, lane = tid & 63;
    const int g = lane >> 4, c = lane & 15;
    const int bid = blockIdx.x;
    const int qtile = bid >> 3, split = bid & 7;  // XCD = bid % 8 = split
    const int tile0 = split * NKV;
    const int rot = ((qtile >> 5) << 4) | ((qtile & 3) << 2);  // stagger offset
    const int othr = tid * 16;                                  // 4KB per load-group
    const int kbase = ((lane & 15) << 6) | ((lane >> 4) << 4);  // c*64 + g*16
    const int vbase = lane << 4;

    // ---- Q B-fragments: B[n=q=c][k = ks*32 + g*8 + j] ----
    f16x8 qf[2][8];
    {
        const size_t qrow0 = (size_t)qtile * QBLK + wave * 32 + c;
#pragma unroll
        for (int mi = 0; mi < 2; ++mi)
#pragma unroll
            for (int ks = 0; ks < 8; ++ks)
                qf[mi][ks] =
                    *(const f16x8*)(Qh + (qrow0 + mi * 16) * D_DIM + (ks * 4 + g) * 8);
    }
    asm volatile("s_waitcnt vmcnt(0)" ::: "memory");  // Q out of the vmcnt pipeline

    f32x4 acc[2][16];
#pragma unroll
    for (int mi = 0; mi < 2; ++mi)
#pragma unroll
        for (int dt = 0; dt < 16; ++dt) acc[mi][dt] = (f32x4){0.f, 0.f, 0.f, 0.f};
    float m[2] = {-1e30f, -1e30f};
    float l[2] = {0.f, 0.f};  // per-lane partials, reduced at epilogue

    // ---- prologue: stage staggered tile 0 into buffer 0 ----
    {
        const int t0 = tile0 + rot;
        const char* Kt = (const char*)Kimg + (size_t)t0 * KTILE_BYTES;
        const char* Vt = (const char*)Vimg + (size_t)t0 * VTILE_BYTES;
#pragma unroll
        for (int i = 0; i < 4; ++i) {
            GLOAD_LDS16(Kt + i * 4096 + othr, smem + i * 4096 + othr);
            GLOAD_LDS16(Vt + i * 4096 + othr, smem + 32768 + i * 4096 + othr);
        }
    }

    for (int kt = 0; kt < NKV; ++kt) {
        const int cur = kt & 1;
        if (kt + 1 < NKV) {
            const int tn = tile0 + ((kt + 1 + rot) & (NKV - 1));
            const char* Kt = (const char*)Kimg + (size_t)tn * KTILE_BYTES;
            const char* Vt = (const char*)Vimg + (size_t)tn * VTILE_BYTES;
            const int nb = (cur ^ 1) * 16384;
#pragma unroll
            for (int i = 0; i < 4; ++i) {
                GLOAD_LDS16(Kt + i * 4096 + othr, smem + nb + i * 4096 + othr);
                GLOAD_LDS16(Vt + i * 4096 + othr, smem + 32768 + nb + i * 4096 + othr);
            }
            asm volatile("s_waitcnt vmcnt(8)" ::: "memory");  // cur landed; next in flight
        } else {
            asm volatile("s_waitcnt vmcnt(0)" ::: "memory");
        }
        __builtin_amdgcn_s_barrier();

        const char* sK = smem + cur * 16384;
        const char* sV = smem + 32768 + cur * 16384;

        // ---- QK^T swapped: st[mi][ct] = S^T[key=ct*16+g*4+r][q=mi*16+c] ----
        f32x4 st[2][2];
#pragma unroll
        for (int mi = 0; mi < 2; ++mi)
#pragma unroll
            for (int ct = 0; ct < 2; ++ct) st[mi][ct] = (f32x4){0.f, 0.f, 0.f, 0.f};
        __builtin_amdgcn_s_setprio(1);
#pragma unroll
        for (int ks = 0; ks < 8; ++ks) {
            f16x8 kf0 = *(const f16x8*)(sK + ks * 2048 + kbase);
            f16x8 kf1 = *(const f16x8*)(sK + ks * 2048 + 1024 + kbase);
            st[0][0] = MFMA16(kf0, qf[0][ks], st[0][0]);
            st[0][1] = MFMA16(kf1, qf[0][ks], st[0][1]);
            st[1][0] = MFMA16(kf0, qf[1][ks], st[1][0]);
            st[1][1] = MFMA16(kf1, qf[1][ks], st[1][1]);
        }
        __builtin_amdgcn_s_setprio(0);

        // ---- online softmax, base-2 (q-row = c; keys spread over g,ct,r) ----
        union PU { unsigned int u[4]; f16x8 v; };
        PU pu[2];
#pragma unroll
        for (int mi = 0; mi < 2; ++mi) {
            float pm = fmaxf(fmaxf(fmaxf(st[mi][0][0], st[mi][0][1]),
                                   fmaxf(st[mi][0][2], st[mi][0][3])),
                             fmaxf(fmaxf(st[mi][1][0], st[mi][1][1]),
                                   fmaxf(st[mi][1][2], st[mi][1][3])));
            if (__any(pm > m[mi] + RESCALE_THR)) {
                pm = fmaxf(pm, __shfl_xor(pm, 16));
                pm = fmaxf(pm, __shfl_xor(pm, 32));
                float mn = fmaxf(m[mi], pm);
                float sc = EXP2(m[mi] - mn);
                m[mi] = mn;
                l[mi] *= sc;
                float fr[4];
#pragma unroll
                for (int r = 0; r < 4; ++r) fr[r] = __shfl(sc, (g << 4) | (g * 4 + r));
#pragma unroll
                for (int dt = 0; dt < 16; ++dt)
#pragma unroll
                    for (int r = 0; r < 4; ++r) acc[mi][dt][r] *= fr[r];
            }
            float rs = 0.f;
#pragma unroll
            for (int ct = 0; ct < 2; ++ct)
#pragma unroll
                for (int r = 0; r < 4; ++r) {
                    float p = EXP2(st[mi][ct][r] - m[mi]);
                    st[mi][ct][r] = p;
                    rs += p;
                }
            l[mi] += rs;
            // pack P in-lane: A'[q=c][kslot g*8+j], pi(g*8+j)=(j>>2)*16+g*4+(j&3)
            pu[mi].u[0] = __builtin_bit_cast(
                unsigned int, __builtin_amdgcn_cvt_pkrtz(st[mi][0][0], st[mi][0][1]));
            pu[mi].u[1] = __builtin_bit_cast(
                unsigned int, __builtin_amdgcn_cvt_pkrtz(st[mi][0][2], st[mi][0][3]));
            pu[mi].u[2] = __builtin_bit_cast(
                unsigned int, __builtin_amdgcn_cvt_pkrtz(st[mi][1][0], st[mi][1][1]));
            pu[mi].u[3] = __builtin_bit_cast(
                unsigned int, __builtin_amdgcn_cvt_pkrtz(st[mi][1][2], st[mi][1][3]));
        }

        // ---- PV: acc[mi][dt] += P' * V'  (linear 1KB wave-reads) ----
        __builtin_amdgcn_s_setprio(1);
#pragma unroll
        for (int dt = 0; dt < 16; ++dt) {
            f16x8 vf = *(const f16x8*)(sV + dt * 1024 + vbase);
            acc[0][dt] = MFMA16(pu[0].v, vf, acc[0][dt]);
            acc[1][dt] = MFMA16(pu[1].v, vf, acc[1][dt]);
        }
        __builtin_amdgcn_s_setprio(0);

        __builtin_amdgcn_s_barrier();  // reads of cur done before next stage overwrites
    }

    // ---- epilogue: unnormalized partial O (f16) + (m,l) ----
    _Float16* Ob = Opart + (size_t)(qtile * TSPLIT + split) * QBLK * D_DIM;
#pragma unroll
    for (int mi = 0; mi < 2; ++mi)
#pragma unroll
        for (int dt = 0; dt < 16; ++dt)
#pragma unroll
            for (int r = 0; r < 4; ++r) {
                int row = wave * 32 + mi * 16 + g * 4 + r;
                int col = dt * 16 + c;
                Ob[(size_t)row * D_DIM + col] = (_Float16)acc[mi][dt][r];
            }
#pragma unroll
    for (int mi = 0; mi < 2; ++mi) {
        l[mi] += __shfl_xor(l[mi], 16);
        l[mi] += __shfl_xor(l[mi], 32);
    }
    if (g == 0) {
        float* mlb = ml + (size_t)((qtile * TSPLIT + split) * QBLK) * 2;
#pragma unroll
        for (int mi = 0; mi < 2; ++mi) {
            int row = wave * 32 + mi * 16 + c;
            mlb[row * 2 + 0] = m[mi];
            mlb[row * 2 + 1] = l[mi];
        }
    }
}

// ---------------- combine TSPLIT partials (base-2 stats) ----------------
__global__ __launch_bounds__(256) void combine_kernel(const _Float16* __restrict__ Opart,
                                                      const float* __restrict__ ml,
                                                      float* __restrict__ out) {
    int r = blockIdx.x;
    int qtile = r >> 7, rl = r & 127;  // QBLK=128
    int d = threadIdx.x;
    float mv[TSPLIT], lv[TSPLIT];
    float M = -1e30f;
#pragma unroll
    for (int s = 0; s < TSPLIT; ++s) {
        const float* mlb = ml + (size_t)((qtile * TSPLIT + s) * QBLK + rl) * 2;
        mv[s] = mlb[0];
        lv[s] = mlb[1];
        M = fmaxf(M, mv[s]);
    }
    float num = 0.f, den = 0.f;
#pragma unroll
    for (int s = 0; s < TSPLIT; ++s) {
        float w = EXP2(mv[s] - M);
        num += w * (float)Opart[((size_t)(qtile * TSPLIT + s) * QBLK + rl) * D_DIM + d];
        den += w * lv[s];
    }
    out[(size_t)r * D_DIM + d] = num / den;
}

extern "C" void kernel_launch(void* const* d_in, const int* in_sizes, int n_in,
                              void* d_out, int out_size, void* d_ws, size_t ws_size,
                              hipStream_t stream) {
    const float* Q = (const float*)d_in[0];
    const float* K = (const float*)d_in[1];
    const float* V = (const float*)d_in[2];
    float* out = (float*)d_out;
    char* ws = (char*)d_ws;

    _Float16* Qh = (_Float16*)ws;                    // 4MB row-major f16 (x log2e)
    _Float16* Kimg = (_Float16*)(ws + (4 << 20));    // 4MB linear-read 32-key tiles
    _Float16* Vimg = (_Float16*)(ws + (8 << 20));    // 4MB linear-read transposed tiles
    _Float16* Opart = (_Float16*)(ws + (12 << 20));  // 32MB f16 partials
    float* ml = (float*)(ws + ((size_t)44 << 20));   // 512KB

    const int n4 = S_LEN * D_DIM / 4;
    const int nchunks = S_LEN * D_DIM / 8;
    cvt_kernel<<<n4 / 256, 256, 0, stream>>>(Q, Qh, n4);
    cvt_swz_kernel<<<nchunks / 256, 256, 0, stream>>>(K, Kimg, nchunks);
    vt_swz_kernel<<<T_LEN / 32, 256, 0, stream>>>(V, Vimg);

    // 512 blocks x 256 threads = 2 blocks/CU; bid&7 = split = XCD id
    attn_kernel<<<NQT * TSPLIT, 256, 0, stream>>>(Qh, Kimg, Vimg, Opart, ml);
    combine_kernel<<<S_LEN, 256, 0, stream>>>(Opart, ml, out);
}